// Round 1
// baseline (847.068 us; speedup 1.0000x reference)
//
#include <hip/hip_runtime.h>
#include <stdint.h>

typedef unsigned int u32;
typedef unsigned long long u64;

#define NCELLS  3872
#define NCLS    80
#define NFLAT   309760
#define NPRE    500
#define NPAD    512
#define HH      200
#define WW      304
#define NPIX    60800
#define NWORDS  950      // 60800 / 64 exactly
#define MSTRIDE 960
#define MAXOUT  100
#define OH      427
#define OW      640
#define MH      800
#define MW      1216
#define MAXG    4096
#define MAXPAIRS 16384
#define OUT_LBL 27328000
#define OUT_SCR 27328100

#define S_THR 0.1f
#define M_THR 0.005f
#define U_THR 0.001f

// ---------------- workspace layout (bytes) ----------------
#define OFF_HIST1   0u        // 65536 u32
#define OFF_HIST2   262144u   // 256 u32
#define OFF_META    263168u   // 16 u32: [0]cut1 [1]cntAbove1 [2]cutKey [3]gatherCnt [4]pairCnt
#define ZERO_BYTES  263232u
#define OFF_CAND    263424u   // 4096 u64
#define OFF_RAW     296192u   // 512 f32
#define OFF_LOC     298240u
#define OFF_LABEL   300288u
#define OFF_XIND    302336u
#define OFF_YIND    304384u
#define OFF_STRIDE  306432u
#define OFF_SMF     308480u
#define OFF_SCORE   310528u
#define OFF_LABELK  312576u
#define OFF_ORDER   314624u
#define OFF_SSCORE  316672u
#define OFF_TOPC    318720u   // 128 i32
#define OFF_PAIRI   319232u   // 16384 u32
#define OFF_PAIRIOU 384768u   // 16384 f32
#define OFF_W1YT0   450304u   // 800 i32
#define OFF_W1YA    453504u   // 800 f32
#define OFF_W1YB    456704u
#define OFF_W1XT0   459904u   // 1216 i32
#define OFF_W1XA    464768u
#define OFF_W1XB    469632u
#define OFF_W2YS    474496u   // 427 i32
#define OFF_W2YW    476224u   // 427*4 f32
#define OFF_W2XS    483072u   // 640 i32
#define OFF_W2XW    485632u   // 640*4 f32
#define OFF_MASKS   495872u   // 500*960 u64  (8-aligned)

#define P_U32(off) ((u32*)(ws + (off)))
#define P_I32(off) ((int*)(ws + (off)))
#define P_F32(off) ((float*)(ws + (off)))
#define P_U64(off) ((u64*)(ws + (off)))

__device__ __forceinline__ void levelMeta(int loc, int& td, int& sd, int& ng, float& st) {
  if (loc < 1600)      { td = 0;    sd = 0;   ng = 40; st = 4.f;  }
  else if (loc < 2896) { td = 1600; sd = 40;  ng = 36; st = 8.f;  }
  else if (loc < 3472) { td = 2896; sd = 76;  ng = 24; st = 16.f; }
  else if (loc < 3728) { td = 3472; sd = 100; ng = 16; st = 32.f; }
  else                 { td = 3728; sd = 116; ng = 12; st = 64.f; }
}

// -------- stage 1: top-500 selection (2-level radix histogram + exact sort) --------
__global__ void kh1(const float* __restrict__ cate, char* __restrict__ ws) {
  int i = blockIdx.x * 256 + threadIdx.x;
  if (i >= NFLAT) return;
  float v = cate[i];
  if (v > S_THR) atomicAdd(&P_U32(OFF_HIST1)[__float_as_uint(v) >> 16], 1u);
}

__global__ __launch_bounds__(1024) void kc1(char* __restrict__ ws) {
  __shared__ u32 cs[1024];
  int t = threadIdx.x;
  const u32* h = P_U32(OFF_HIST1);
  u32 s = 0;
  for (int b = 0; b < 64; b++) s += h[t * 64 + b];
  cs[t] = s;
  __syncthreads();
  if (t == 0) {
    u32* meta = P_U32(OFF_META);
    u32 cum = 0; int cb = -1;
    for (int c = 1023; c >= 0; c--) {
      if (cum + cs[c] >= NPRE) { cb = c; break; }
      cum += cs[c];
    }
    if (cb < 0) { meta[0] = 0u; meta[1] = cum; }
    else {
      int bin = cb * 64;
      for (int b = cb * 64 + 63; b >= cb * 64; b--) {
        u32 hb = h[b];
        if (cum + hb >= NPRE) { bin = b; break; }
        cum += hb;
      }
      meta[0] = (u32)bin; meta[1] = cum;
    }
  }
}

__global__ void kh2(const float* __restrict__ cate, char* __restrict__ ws) {
  u32 cut1 = P_U32(OFF_META)[0];
  int i = blockIdx.x * 256 + threadIdx.x;
  if (i >= NFLAT) return;
  float v = cate[i];
  if (v > S_THR) {
    u32 b = __float_as_uint(v);
    if ((b >> 16) == cut1) atomicAdd(&P_U32(OFF_HIST2)[(b >> 8) & 0xffu], 1u);
  }
}

__global__ void kc2(char* __restrict__ ws) {
  u32* meta = P_U32(OFF_META);
  const u32* h2 = P_U32(OFF_HIST2);
  u32 need = NPRE - meta[1];
  u32 cum = 0;
  u32 key = meta[0] << 16;
  for (int s = 255; s >= 0; s--) {
    cum += h2[s];
    if (cum >= need) { key = (meta[0] << 16) | ((u32)s << 8); break; }
  }
  meta[2] = key;
}

__global__ void kg(const float* __restrict__ cate, char* __restrict__ ws) {
  u32 key = P_U32(OFF_META)[2];
  int i = blockIdx.x * 256 + threadIdx.x;
  if (i >= NFLAT) return;
  float v = cate[i];
  if (v > S_THR) {
    u32 b = __float_as_uint(v);
    if (b >= key) {
      u32 pos = atomicAdd(&P_U32(OFF_META)[3], 1u);
      if (pos < MAXG) P_U64(OFF_CAND)[pos] = (((u64)b) << 32) | (u32)(~(u32)i);
    }
  }
}

__global__ __launch_bounds__(1024) void ksel(char* __restrict__ ws) {
  __shared__ u64 sk[MAXG];
  int tid = threadIdx.x;
  int G = (int)P_U32(OFF_META)[3]; if (G > MAXG) G = MAXG;
  const u64* cand = P_U64(OFF_CAND);
  for (int i = tid; i < MAXG; i += 1024) sk[i] = (i < G) ? cand[i] : 0ull;
  __syncthreads();
  for (int k = 2; k <= MAXG; k <<= 1) {
    for (int j = k >> 1; j > 0; j >>= 1) {
      for (int i = tid; i < MAXG; i += 1024) {
        int l = i ^ j;
        if (l > i) {
          u64 a = sk[i], b = sk[l];
          bool sw = ((i & k) == 0) ? (a < b) : (a > b);
          if (sw) { sk[i] = b; sk[l] = a; }
        }
      }
      __syncthreads();
    }
  }
  if (tid < NPAD) {
    float rawv = -1.f; int loc = 0, lab = -1, xi = 0, yi = 0; float st = 3.0e38f;
    if (tid < NPRE && tid < G) {
      u64 key = sk[tid];
      u32 b = (u32)(key >> 32);
      u32 idx = ~((u32)(key & 0xffffffffu));
      rawv = __uint_as_float(b);
      loc = (int)(idx / (u32)NCLS);
      lab = (int)(idx - (u32)loc * NCLS);
      int td, sd, ng; levelMeta(loc, td, sd, ng, st);
      int rel = loc - td;
      int row = rel / ng;
      yi = row + sd;
      xi = (rel - row * ng) + sd;
    }
    P_F32(OFF_RAW)[tid] = rawv;
    P_I32(OFF_LOC)[tid] = loc;
    P_I32(OFF_LABEL)[tid] = lab;
    P_I32(OFF_XIND)[tid] = xi;
    P_I32(OFF_YIND)[tid] = yi;
    P_F32(OFF_STRIDE)[tid] = st;
    P_F32(OFF_SCORE)[tid] = 0.f;
    P_I32(OFF_LABELK)[tid] = -1;
    P_F32(OFF_SMF)[tid] = 0.f;
  }
}

// -------- stage 2: per-candidate bit-packed mask + seg-score --------
__global__ __launch_bounds__(256) void kmask(const float* __restrict__ segx, const float* __restrict__ segy,
                                             char* __restrict__ ws) {
  int c = blockIdx.x;
  int tid = threadIdx.x;
  int lane = tid & 63, wv = tid >> 6;
  const float* X = segx + (size_t)P_I32(OFF_XIND)[c] * NPIX;
  const float* Y = segy + (size_t)P_I32(OFF_YIND)[c] * NPIX;
  u64* mrow = P_U64(OFF_MASKS) + (size_t)c * MSTRIDE;
  int cnt = 0;
  double ssum = 0.0;
  for (int w0 = wv; w0 < NWORDS; w0 += 4) {
    int p = (w0 << 6) + lane;
    float s = X[p] * Y[p];
    bool b = s > M_THR;
    u64 bal = __ballot(b ? 1 : 0);
    if (lane == 0) mrow[w0] = bal;
    if (b) { cnt++; ssum += (double)s; }
  }
  __shared__ int ci[256];
  __shared__ double cd[256];
  ci[tid] = cnt; cd[tid] = ssum;
  __syncthreads();
  for (int s2 = 128; s2 > 0; s2 >>= 1) {
    if (tid < s2) { ci[tid] += ci[tid + s2]; cd[tid] += cd[tid + s2]; }
    __syncthreads();
  }
  if (tid == 0) {
    float sm = (float)ci[0];
    float rawv = P_F32(OFF_RAW)[c];
    bool valid = rawv > S_THR;
    bool keep = valid && (sm > P_F32(OFF_STRIDE)[c]);
    float ssf = (float)cd[0];
    float segsc = ssf / fmaxf(sm, 1e-6f);
    P_F32(OFF_SCORE)[c] = keep ? (rawv * segsc) : 0.f;
    P_F32(OFF_SMF)[c] = keep ? sm : 0.f;
    P_I32(OFF_LABELK)[c] = keep ? P_I32(OFF_LABEL)[c] : -1;
  }
}

// -------- stage 3: stable descending sort of 500 scores --------
__global__ __launch_bounds__(512) void ksort500(char* __restrict__ ws) {
  __shared__ u64 sk[NPAD];
  int t = threadIdx.x;
  float sc = (t < NPRE) ? P_F32(OFF_SCORE)[t] : 0.f;
  sk[t] = (((u64)__float_as_uint(sc)) << 32) | (u32)(NPAD - 1 - t);
  __syncthreads();
  for (int k = 2; k <= NPAD; k <<= 1) {
    for (int j = k >> 1; j > 0; j >>= 1) {
      int l = t ^ j;
      if (l > t) {
        u64 a = sk[t], b = sk[l];
        bool sw = ((t & k) == 0) ? (a < b) : (a > b);
        if (sw) { sk[t] = b; sk[l] = a; }
      }
      __syncthreads();
    }
  }
  P_I32(OFF_ORDER)[t] = NPAD - 1 - (int)(sk[t] & 0xffffffffu);
  P_F32(OFF_SSCORE)[t] = __uint_as_float((u32)(sk[t] >> 32));
}

// -------- stage 4: same-class ordered pairs + popcount IoU --------
__global__ __launch_bounds__(512) void kpairs(char* __restrict__ ws) {
  int j = threadIdx.x;
  if (j >= NPRE) return;
  const int* order = P_I32(OFF_ORDER);
  const int* labelK = P_I32(OFF_LABELK);
  int labj = labelK[order[j]];
  if (labj < 0) return;
  for (int i = 0; i < j; i++) {
    if (labelK[order[i]] == labj) {
      u32 pos = atomicAdd(&P_U32(OFF_META)[4], 1u);
      if (pos < MAXPAIRS) P_U32(OFF_PAIRI)[pos] = (((u32)i) << 16) | (u32)j;
    }
  }
}

__global__ __launch_bounds__(64) void kpiou(char* __restrict__ ws) {
  int P = (int)P_U32(OFF_META)[4]; if (P > MAXPAIRS) P = MAXPAIRS;
  const int* order = P_I32(OFF_ORDER);
  const float* smf = P_F32(OFF_SMF);
  const u64* masks = P_U64(OFF_MASKS);
  for (int p = blockIdx.x; p < P; p += gridDim.x) {
    u32 ij = P_U32(OFF_PAIRI)[p];
    int oi = order[ij >> 16];
    int oj = order[ij & 0xffffu];
    const u64* mi = masks + (size_t)oi * MSTRIDE;
    const u64* mj = masks + (size_t)oj * MSTRIDE;
    int inter = 0;
    for (int w = threadIdx.x; w < NWORDS; w += 64)
      inter += (int)__popcll(mi[w] & mj[w]);
    for (int off = 32; off > 0; off >>= 1)
      inter += __shfl_down(inter, off);
    if (threadIdx.x == 0) {
      float fi = (float)inter;
      float uni = (smf[oj] + smf[oi]) - fi;
      float iou = (uni > 0.f) ? (fi / fmaxf(uni, 1e-12f)) : 0.f;
      P_F32(OFF_PAIRIOU)[p] = iou;
    }
  }
}

// -------- stage 5: matrix-NMS decay + top-100 + labels/scores out --------
__global__ __launch_bounds__(512) void knms(char* __restrict__ ws, float* __restrict__ out) {
  __shared__ int compI[NPAD];
  __shared__ int coefI[NPAD];
  __shared__ u64 sk[NPAD];
  int t = threadIdx.x;
  int P = (int)P_U32(OFF_META)[4]; if (P > MAXPAIRS) P = MAXPAIRS;
  const u32* pairI = P_U32(OFF_PAIRI);
  const float* pairIou = P_F32(OFF_PAIRIOU);
  const float* sscore = P_F32(OFF_SSCORE);
  const int* order = P_I32(OFF_ORDER);
  const int* labelK = P_I32(OFF_LABELK);
  int* topc = P_I32(OFF_TOPC);
  compI[t] = 0;                       // bits of 0.0f
  coefI[t] = __float_as_int(1.0f);
  __syncthreads();
  for (int p = t; p < P; p += 512) {
    int j = (int)(pairI[p] & 0xffffu);
    atomicMax(&compI[j], __float_as_int(pairIou[p]));
  }
  __syncthreads();
  for (int p = t; p < P; p += 512) {
    u32 ij = pairI[p];
    int i = (int)(ij >> 16), j = (int)(ij & 0xffffu);
    float x = pairIou[p];
    float c = __int_as_float(compI[i]);
    float x2 = x * x, c2 = c * c;
    float r = (float)exp(-2.0 * ((double)x2 - (double)c2));
    atomicMin(&coefI[j], __float_as_int(r));
  }
  __syncthreads();
  float ns = 0.f;
  if (t < NPRE) {
    ns = sscore[t] * __int_as_float(coefI[t]);
    ns = (ns > U_THR) ? ns : 0.f;
  }
  sk[t] = (((u64)__float_as_uint(ns)) << 32) | (u32)(NPAD - 1 - t);
  __syncthreads();
  for (int k = 2; k <= NPAD; k <<= 1) {
    for (int j = k >> 1; j > 0; j >>= 1) {
      int l = t ^ j;
      if (l > t) {
        u64 a = sk[t], b = sk[l];
        bool sw = ((t & k) == 0) ? (a < b) : (a > b);
        if (sw) { sk[t] = b; sk[l] = a; }
      }
      __syncthreads();
    }
  }
  if (t < MAXOUT) {
    u64 key = sk[t];
    int pos = NPAD - 1 - (int)(key & 0xffffffffu);
    int cand = order[pos];
    topc[t] = cand;
    out[OUT_LBL + t] = (float)labelK[cand];
    out[OUT_SCR + t] = __uint_as_float((u32)(key >> 32));
  }
}

// -------- stage 6: resize weight tables (mimic jax.image.resize f32 math) --------
__global__ __launch_bounds__(1024) void kwts(char* __restrict__ ws) {
  int t = threadIdx.x;
  // resize1 y mid rows: 200 -> 800 (bilinear, 2 taps, border-renormalized)
  for (int r = t; r < MH; r += 1024) {
    float s1 = ((float)r + 0.5f) * 0.25f - 0.5f;
    int t0 = (int)floorf(s1);
    float f = s1 - (float)t0;
    float wa = 1.f - f, wb = f;
    bool ia = (t0 >= 0) && (t0 < HH);
    bool ib = ((t0 + 1) >= 0) && ((t0 + 1) < HH);
    float tw = (ia ? wa : 0.f) + (ib ? wb : 0.f);
    float na = ia ? (wa / tw) : 0.f;
    float nb = ib ? (wb / tw) : 0.f;
    int base; float A, B;
    if (t0 < 0) { base = 0; A = nb; B = 0.f; }
    else if (t0 >= HH - 1) { base = HH - 2; A = 0.f; B = na; }
    else { base = t0; A = na; B = nb; }
    P_I32(OFF_W1YT0)[r] = base;
    P_F32(OFF_W1YA)[r] = A;
    P_F32(OFF_W1YB)[r] = B;
  }
  // resize1 x mid cols: 304 -> 1216
  for (int c = t; c < MW; c += 1024) {
    float s1 = ((float)c + 0.5f) * 0.25f - 0.5f;
    int t0 = (int)floorf(s1);
    float f = s1 - (float)t0;
    float wa = 1.f - f, wb = f;
    bool ia = (t0 >= 0) && (t0 < WW);
    bool ib = ((t0 + 1) >= 0) && ((t0 + 1) < WW);
    float tw = (ia ? wa : 0.f) + (ib ? wb : 0.f);
    float na = ia ? (wa / tw) : 0.f;
    float nb = ib ? (wb / tw) : 0.f;
    int base; float A, B;
    if (t0 < 0) { base = 0; A = nb; B = 0.f; }
    else if (t0 >= WW - 1) { base = WW - 2; A = 0.f; B = na; }
    else { base = t0; A = na; B = nb; }
    P_I32(OFF_W1XT0)[c] = base;
    P_F32(OFF_W1XA)[c] = A;
    P_F32(OFF_W1XB)[c] = B;
  }
  // resize2 y: 800 -> 427 (antialias triangle, kernel_scale = 800/427, <=4 taps)
  for (int o = t; o < OH; o += 1024) {
    const float inv = (float)(800.0 / 427.0);
    float s2 = ((float)o + 0.5f) * inv - 0.5f;
    int rA = (int)ceilf(s2 - inv);
    int rB = (int)floorf(s2 + inv);
    if (rA < 0) rA = 0;
    if (rB > MH - 1) rB = MH - 1;
    float tot = 0.f;
    for (int r = rA; r <= rB; r++) {
      float x = fabsf(s2 - (float)r) / inv;
      float w = 1.f - x; if (w < 0.f) w = 0.f;
      tot += w;
    }
    int base = rA; if (base > MH - 4) base = MH - 4;
    float o4[4] = {0.f, 0.f, 0.f, 0.f};
    for (int r = rA; r <= rB; r++) {
      float x = fabsf(s2 - (float)r) / inv;
      float w = 1.f - x; if (w < 0.f) w = 0.f;
      o4[r - base] += w / tot;
    }
    P_I32(OFF_W2YS)[o] = base;
    float* wp = P_F32(OFF_W2YW) + o * 4;
    wp[0] = o4[0]; wp[1] = o4[1]; wp[2] = o4[2]; wp[3] = o4[3];
  }
  // resize2 x: 1216 -> 640 (kernel_scale = 1.9)
  for (int o = t; o < OW; o += 1024) {
    const float inv = (float)(1216.0 / 640.0);
    float s2 = ((float)o + 0.5f) * inv - 0.5f;
    int rA = (int)ceilf(s2 - inv);
    int rB = (int)floorf(s2 + inv);
    if (rA < 0) rA = 0;
    if (rB > MW - 1) rB = MW - 1;
    float tot = 0.f;
    for (int r = rA; r <= rB; r++) {
      float x = fabsf(s2 - (float)r) / inv;
      float w = 1.f - x; if (w < 0.f) w = 0.f;
      tot += w;
    }
    int base = rA; if (base > MW - 4) base = MW - 4;
    float o4[4] = {0.f, 0.f, 0.f, 0.f};
    for (int r = rA; r <= rB; r++) {
      float x = fabsf(s2 - (float)r) / inv;
      float w = 1.f - x; if (w < 0.f) w = 0.f;
      o4[r - base] += w / tot;
    }
    P_I32(OFF_W2XS)[o] = base;
    float* wp = P_F32(OFF_W2XW) + o * 4;
    wp[0] = o4[0]; wp[1] = o4[1]; wp[2] = o4[2]; wp[3] = o4[3];
  }
}

// -------- stage 7: fused double-resize + binarize, one block per (mask, out-row) --------
__global__ __launch_bounds__(256) void kout(const float* __restrict__ segx, const float* __restrict__ segy,
                                            char* __restrict__ ws, float* __restrict__ out) {
  __shared__ float t1[4][WW];   // stage-1 vertical transform of the 4 needed mid rows
  __shared__ float up[4][MW];   // full mid-resolution rows (f32-rounded like the reference)
  int bx = blockIdx.x;
  int kk = bx / OH;
  int oy = bx - kk * OH;
  int tid = threadIdx.x;
  int cand = P_I32(OFF_TOPC)[kk];
  const float* X = segx + (size_t)P_I32(OFF_XIND)[cand] * NPIX;
  const float* Y = segy + (size_t)P_I32(OFF_YIND)[cand] * NPIX;
  int rbase = P_I32(OFF_W2YS)[oy];
  const int* w1yT0 = P_I32(OFF_W1YT0);
  const float* w1yA = P_F32(OFF_W1YA);
  const float* w1yB = P_F32(OFF_W1YB);
  for (int idx = tid; idx < 4 * WW; idx += 256) {
    int m = idx / WW;
    int u = idx - m * WW;
    int r = rbase + m;
    int t0 = w1yT0[r];
    float A = w1yA[r], B = w1yB[r];
    float s0 = X[t0 * WW + u] * Y[t0 * WW + u];
    float s1 = X[(t0 + 1) * WW + u] * Y[(t0 + 1) * WW + u];
    t1[m][u] = fmaf(B, s1, A * s0);
  }
  __syncthreads();
  const int* w1xT0 = P_I32(OFF_W1XT0);
  const float* w1xA = P_F32(OFF_W1XA);
  const float* w1xB = P_F32(OFF_W1XB);
  for (int idx = tid; idx < 4 * MW; idx += 256) {
    int m = idx / MW;
    int cc = idx - m * MW;
    int u0 = w1xT0[cc];
    up[m][cc] = fmaf(w1xB[cc], t1[m][u0 + 1], w1xA[cc] * t1[m][u0]);
  }
  __syncthreads();
  float wy[4];
  {
    const float* wyp = P_F32(OFF_W2YW) + oy * 4;
    wy[0] = wyp[0]; wy[1] = wyp[1]; wy[2] = wyp[2]; wy[3] = wyp[3];
  }
  const int* w2xS = P_I32(OFF_W2XS);
  const float* w2xW = P_F32(OFF_W2XW);
  size_t obase = ((size_t)kk * OH + oy) * OW;
  for (int ox = tid; ox < OW; ox += 256) {
    int cb = w2xS[ox];
    const float* wx = w2xW + ox * 4;
    float acc = 0.f;
    #pragma unroll
    for (int q = 0; q < 4; q++) {
      int cc = cb + q;
      float t2 = 0.f;
      #pragma unroll
      for (int m = 0; m < 4; m++) t2 = fmaf(wy[m], up[m][cc], t2);
      acc = fmaf(wx[q], t2, acc);
    }
    out[obase + ox] = (acc > M_THR) ? 1.0f : 0.0f;
  }
}

extern "C" void kernel_launch(void* const* d_in, const int* in_sizes, int n_in,
                              void* d_out, int out_size, void* d_ws, size_t ws_size,
                              hipStream_t stream) {
  (void)in_sizes; (void)n_in; (void)out_size; (void)ws_size;
  const float* cate = (const float*)d_in[0];
  const float* segx = (const float*)d_in[1];
  const float* segy = (const float*)d_in[2];
  char* ws = (char*)d_ws;
  float* out = (float*)d_out;

  hipMemsetAsync(ws, 0, ZERO_BYTES, stream);

  dim3 gFlat((NFLAT + 255) / 256);
  hipLaunchKernelGGL(kh1, gFlat, dim3(256), 0, stream, cate, ws);
  hipLaunchKernelGGL(kc1, dim3(1), dim3(1024), 0, stream, ws);
  hipLaunchKernelGGL(kh2, gFlat, dim3(256), 0, stream, cate, ws);
  hipLaunchKernelGGL(kc2, dim3(1), dim3(1), 0, stream, ws);
  hipLaunchKernelGGL(kg, gFlat, dim3(256), 0, stream, cate, ws);
  hipLaunchKernelGGL(ksel, dim3(1), dim3(1024), 0, stream, ws);
  hipLaunchKernelGGL(kmask, dim3(NPRE), dim3(256), 0, stream, segx, segy, ws);
  hipLaunchKernelGGL(ksort500, dim3(1), dim3(512), 0, stream, ws);
  hipLaunchKernelGGL(kpairs, dim3(1), dim3(512), 0, stream, ws);
  hipLaunchKernelGGL(kpiou, dim3(2048), dim3(64), 0, stream, ws);
  hipLaunchKernelGGL(kwts, dim3(1), dim3(1024), 0, stream, ws);
  hipLaunchKernelGGL(knms, dim3(1), dim3(512), 0, stream, ws, out);
  hipLaunchKernelGGL(kout, dim3(MAXOUT * OH), dim3(256), 0, stream, segx, segy, ws, out);
}

// Round 2
// 631.767 us; speedup vs baseline: 1.3408x; 1.3408x over previous
//
#include <hip/hip_runtime.h>
#include <stdint.h>

typedef unsigned int u32;
typedef unsigned long long u64;

#define NCELLS  3872
#define NCLS    80
#define NFLAT   309760
#define NPRE    500
#define NPAD    512
#define HH      200
#define WW      304
#define NPIX    60800
#define NWORDS  950      // 60800 / 64 exactly
#define MSTRIDE 960
#define MAXOUT  100
#define OH      427
#define OW      640
#define MH      800
#define MW      1216
#define MAXG    4096
#define MAXPAIRS 16384
#define OUT_LBL 27328000
#define OUT_SCR 27328100

#define S_THR 0.1f
#define M_THR 0.005f
#define U_THR 0.001f

// ---------------- workspace layout (bytes) ----------------
#define OFF_HIST1   0u        // 65536 u32
#define OFF_HIST2   262144u   // 256 u32
#define OFF_META    263168u   // 16 u32: [0]cut1 [1]cntAbove1 [2]cutKey [3]gatherCnt [4]pairCnt
#define ZERO_BYTES  263232u
#define OFF_CAND    263424u   // 4096 u64
#define OFF_RAW     296192u   // 512 f32
#define OFF_LOC     298240u
#define OFF_LABEL   300288u
#define OFF_XIND    302336u
#define OFF_YIND    304384u
#define OFF_STRIDE  306432u
#define OFF_SMF     308480u
#define OFF_SCORE   310528u
#define OFF_LABELK  312576u
#define OFF_ORDER   314624u
#define OFF_SSCORE  316672u
#define OFF_TOPC    318720u   // 128 i32
#define OFF_PAIRI   319232u   // 16384 u32
#define OFF_PAIRIOU 384768u   // 16384 f32
#define OFF_W1YT0   450304u   // 800 i32
#define OFF_W1YA    453504u   // 800 f32
#define OFF_W1YB    456704u
#define OFF_W1XT0   459904u   // 1216 i32
#define OFF_W1XA    464768u
#define OFF_W1XB    469632u
#define OFF_W2YS    474496u   // 427 i32
#define OFF_W2YW    476224u   // 427*4 f32
#define OFF_W2XS    483072u   // 640 i32
#define OFF_W2XW    485632u   // 640*4 f32
#define OFF_MASKS   495872u   // 500*960 u64  (8-aligned)

#define P_U32(off) ((u32*)(ws + (off)))
#define P_I32(off) ((int*)(ws + (off)))
#define P_F32(off) ((float*)(ws + (off)))
#define P_U64(off) ((u64*)(ws + (off)))

__device__ __forceinline__ void levelMeta(int loc, int& td, int& sd, int& ng, float& st) {
  if (loc < 1600)      { td = 0;    sd = 0;   ng = 40; st = 4.f;  }
  else if (loc < 2896) { td = 1600; sd = 40;  ng = 36; st = 8.f;  }
  else if (loc < 3472) { td = 2896; sd = 76;  ng = 24; st = 16.f; }
  else if (loc < 3728) { td = 3472; sd = 100; ng = 16; st = 32.f; }
  else                 { td = 3728; sd = 116; ng = 12; st = 64.f; }
}

// -------- stage 1: top-500 selection (2-level radix histogram + exact sort) --------
__global__ void kh1(const float* __restrict__ cate, char* __restrict__ ws) {
  int i = blockIdx.x * 256 + threadIdx.x;
  if (i >= NFLAT) return;
  float v = cate[i];
  if (v > S_THR) atomicAdd(&P_U32(OFF_HIST1)[__float_as_uint(v) >> 16], 1u);
}

__global__ __launch_bounds__(1024) void kc1(char* __restrict__ ws) {
  __shared__ u32 cs[1024];
  int t = threadIdx.x;
  const u32* h = P_U32(OFF_HIST1);
  u32 s = 0;
  for (int b = 0; b < 64; b++) s += h[t * 64 + b];
  cs[t] = s;
  __syncthreads();
  if (t == 0) {
    u32* meta = P_U32(OFF_META);
    u32 cum = 0; int cb = -1;
    for (int c = 1023; c >= 0; c--) {
      if (cum + cs[c] >= NPRE) { cb = c; break; }
      cum += cs[c];
    }
    if (cb < 0) { meta[0] = 0u; meta[1] = cum; }
    else {
      int bin = cb * 64;
      for (int b = cb * 64 + 63; b >= cb * 64; b--) {
        u32 hb = h[b];
        if (cum + hb >= NPRE) { bin = b; break; }
        cum += hb;
      }
      meta[0] = (u32)bin; meta[1] = cum;
    }
  }
}

__global__ void kh2(const float* __restrict__ cate, char* __restrict__ ws) {
  u32 cut1 = P_U32(OFF_META)[0];
  int i = blockIdx.x * 256 + threadIdx.x;
  if (i >= NFLAT) return;
  float v = cate[i];
  if (v > S_THR) {
    u32 b = __float_as_uint(v);
    if ((b >> 16) == cut1) atomicAdd(&P_U32(OFF_HIST2)[(b >> 8) & 0xffu], 1u);
  }
}

__global__ void kc2(char* __restrict__ ws) {
  u32* meta = P_U32(OFF_META);
  const u32* h2 = P_U32(OFF_HIST2);
  u32 need = NPRE - meta[1];
  u32 cum = 0;
  u32 key = meta[0] << 16;
  for (int s = 255; s >= 0; s--) {
    cum += h2[s];
    if (cum >= need) { key = (meta[0] << 16) | ((u32)s << 8); break; }
  }
  meta[2] = key;
}

__global__ void kg(const float* __restrict__ cate, char* __restrict__ ws) {
  u32 key = P_U32(OFF_META)[2];
  int i = blockIdx.x * 256 + threadIdx.x;
  if (i >= NFLAT) return;
  float v = cate[i];
  if (v > S_THR) {
    u32 b = __float_as_uint(v);
    if (b >= key) {
      u32 pos = atomicAdd(&P_U32(OFF_META)[3], 1u);
      if (pos < MAXG) P_U64(OFF_CAND)[pos] = (((u64)b) << 32) | (u32)(~(u32)i);
    }
  }
}

__global__ __launch_bounds__(1024) void ksel(char* __restrict__ ws) {
  __shared__ u64 sk[MAXG];
  int tid = threadIdx.x;
  int G = (int)P_U32(OFF_META)[3]; if (G > MAXG) G = MAXG;
  const u64* cand = P_U64(OFF_CAND);
  for (int i = tid; i < MAXG; i += 1024) sk[i] = (i < G) ? cand[i] : 0ull;
  __syncthreads();
  for (int k = 2; k <= MAXG; k <<= 1) {
    for (int j = k >> 1; j > 0; j >>= 1) {
      for (int i = tid; i < MAXG; i += 1024) {
        int l = i ^ j;
        if (l > i) {
          u64 a = sk[i], b = sk[l];
          bool sw = ((i & k) == 0) ? (a < b) : (a > b);
          if (sw) { sk[i] = b; sk[l] = a; }
        }
      }
      __syncthreads();
    }
  }
  if (tid < NPAD) {
    float rawv = -1.f; int loc = 0, lab = -1, xi = 0, yi = 0; float st = 3.0e38f;
    if (tid < NPRE && tid < G) {
      u64 key = sk[tid];
      u32 b = (u32)(key >> 32);
      u32 idx = ~((u32)(key & 0xffffffffu));
      rawv = __uint_as_float(b);
      loc = (int)(idx / (u32)NCLS);
      lab = (int)(idx - (u32)loc * NCLS);
      int td, sd, ng; levelMeta(loc, td, sd, ng, st);
      int rel = loc - td;
      int row = rel / ng;
      yi = row + sd;
      xi = (rel - row * ng) + sd;
    }
    P_F32(OFF_RAW)[tid] = rawv;
    P_I32(OFF_LOC)[tid] = loc;
    P_I32(OFF_LABEL)[tid] = lab;
    P_I32(OFF_XIND)[tid] = xi;
    P_I32(OFF_YIND)[tid] = yi;
    P_F32(OFF_STRIDE)[tid] = st;
    P_F32(OFF_SCORE)[tid] = 0.f;
    P_I32(OFF_LABELK)[tid] = -1;
    P_F32(OFF_SMF)[tid] = 0.f;
  }
}

// -------- stage 2: per-candidate bit-packed mask + seg-score --------
__global__ __launch_bounds__(256) void kmask(const float* __restrict__ segx, const float* __restrict__ segy,
                                             char* __restrict__ ws) {
  int c = blockIdx.x;
  int tid = threadIdx.x;
  int lane = tid & 63, wv = tid >> 6;
  const float* X = segx + (size_t)P_I32(OFF_XIND)[c] * NPIX;
  const float* Y = segy + (size_t)P_I32(OFF_YIND)[c] * NPIX;
  u64* mrow = P_U64(OFF_MASKS) + (size_t)c * MSTRIDE;
  int cnt = 0;
  double ssum = 0.0;
  for (int w0 = wv; w0 < NWORDS; w0 += 4) {
    int p = (w0 << 6) + lane;
    float s = X[p] * Y[p];
    bool b = s > M_THR;
    u64 bal = __ballot(b ? 1 : 0);
    if (lane == 0) mrow[w0] = bal;
    if (b) { cnt++; ssum += (double)s; }
  }
  __shared__ int ci[256];
  __shared__ double cd[256];
  ci[tid] = cnt; cd[tid] = ssum;
  __syncthreads();
  for (int s2 = 128; s2 > 0; s2 >>= 1) {
    if (tid < s2) { ci[tid] += ci[tid + s2]; cd[tid] += cd[tid + s2]; }
    __syncthreads();
  }
  if (tid == 0) {
    float sm = (float)ci[0];
    float rawv = P_F32(OFF_RAW)[c];
    bool valid = rawv > S_THR;
    bool keep = valid && (sm > P_F32(OFF_STRIDE)[c]);
    float ssf = (float)cd[0];
    float segsc = ssf / fmaxf(sm, 1e-6f);
    P_F32(OFF_SCORE)[c] = keep ? (rawv * segsc) : 0.f;
    P_F32(OFF_SMF)[c] = keep ? sm : 0.f;
    P_I32(OFF_LABELK)[c] = keep ? P_I32(OFF_LABEL)[c] : -1;
  }
}

// -------- stage 3: stable descending sort of 500 scores --------
__global__ __launch_bounds__(512) void ksort500(char* __restrict__ ws) {
  __shared__ u64 sk[NPAD];
  int t = threadIdx.x;
  float sc = (t < NPRE) ? P_F32(OFF_SCORE)[t] : 0.f;
  sk[t] = (((u64)__float_as_uint(sc)) << 32) | (u32)(NPAD - 1 - t);
  __syncthreads();
  for (int k = 2; k <= NPAD; k <<= 1) {
    for (int j = k >> 1; j > 0; j >>= 1) {
      int l = t ^ j;
      if (l > t) {
        u64 a = sk[t], b = sk[l];
        bool sw = ((t & k) == 0) ? (a < b) : (a > b);
        if (sw) { sk[t] = b; sk[l] = a; }
      }
      __syncthreads();
    }
  }
  P_I32(OFF_ORDER)[t] = NPAD - 1 - (int)(sk[t] & 0xffffffffu);
  P_F32(OFF_SSCORE)[t] = __uint_as_float((u32)(sk[t] >> 32));
}

// -------- stage 4: same-class ordered pairs (LDS labels + prefix-sum write) --------
__global__ __launch_bounds__(512) void kpairs(char* __restrict__ ws) {
  __shared__ short slab[NPAD];
  __shared__ u32 scan[NPAD];
  int t = threadIdx.x;
  const int* order = P_I32(OFF_ORDER);
  const int* labelK = P_I32(OFF_LABELK);
  int lab = -1;
  if (t < NPRE) lab = labelK[order[t]];
  slab[t] = (short)lab;
  __syncthreads();
  u32 cnt = 0;
  if (lab >= 0) {
    short lj = (short)lab;
    for (int i = 0; i < t; i++) if (slab[i] == lj) cnt++;
  }
  scan[t] = cnt;
  __syncthreads();
  // Hillis-Steele inclusive scan over 512
  for (int off = 1; off < NPAD; off <<= 1) {
    u32 v = (t >= off) ? scan[t - off] : 0u;
    __syncthreads();
    scan[t] += v;
    __syncthreads();
  }
  if (t == NPAD - 1) {
    u32 tot = scan[t];
    P_U32(OFF_META)[4] = (tot > MAXPAIRS) ? MAXPAIRS : tot;
  }
  if (lab >= 0 && cnt) {
    u32 pos = scan[t] - cnt;     // exclusive prefix = this thread's base
    short lj = (short)lab;
    u32* pairI = P_U32(OFF_PAIRI);
    for (int i = 0; i < t; i++) {
      if (slab[i] == lj) {
        if (pos < MAXPAIRS) pairI[pos] = (((u32)i) << 16) | (u32)t;
        pos++;
      }
    }
  }
}

__global__ __launch_bounds__(64) void kpiou(char* __restrict__ ws) {
  int P = (int)P_U32(OFF_META)[4]; if (P > MAXPAIRS) P = MAXPAIRS;
  const int* order = P_I32(OFF_ORDER);
  const float* smf = P_F32(OFF_SMF);
  const u64* masks = P_U64(OFF_MASKS);
  for (int p = blockIdx.x; p < P; p += gridDim.x) {
    u32 ij = P_U32(OFF_PAIRI)[p];
    int oi = order[ij >> 16];
    int oj = order[ij & 0xffffu];
    const u64* mi = masks + (size_t)oi * MSTRIDE;
    const u64* mj = masks + (size_t)oj * MSTRIDE;
    int inter = 0;
    for (int w = threadIdx.x; w < NWORDS; w += 64)
      inter += (int)__popcll(mi[w] & mj[w]);
    for (int off = 32; off > 0; off >>= 1)
      inter += __shfl_down(inter, off);
    if (threadIdx.x == 0) {
      float fi = (float)inter;
      float uni = (smf[oj] + smf[oi]) - fi;
      float iou = (uni > 0.f) ? (fi / fmaxf(uni, 1e-12f)) : 0.f;
      P_F32(OFF_PAIRIOU)[p] = iou;
    }
  }
}

// -------- stage 5: matrix-NMS decay + top-100 + labels/scores out --------
__global__ __launch_bounds__(512) void knms(char* __restrict__ ws, float* __restrict__ out) {
  __shared__ int compI[NPAD];
  __shared__ int coefI[NPAD];
  __shared__ u64 sk[NPAD];
  int t = threadIdx.x;
  int P = (int)P_U32(OFF_META)[4]; if (P > MAXPAIRS) P = MAXPAIRS;
  const u32* pairI = P_U32(OFF_PAIRI);
  const float* pairIou = P_F32(OFF_PAIRIOU);
  const float* sscore = P_F32(OFF_SSCORE);
  const int* order = P_I32(OFF_ORDER);
  const int* labelK = P_I32(OFF_LABELK);
  int* topc = P_I32(OFF_TOPC);
  compI[t] = 0;                       // bits of 0.0f
  coefI[t] = __float_as_int(1.0f);
  __syncthreads();
  for (int p = t; p < P; p += 512) {
    int j = (int)(pairI[p] & 0xffffu);
    atomicMax(&compI[j], __float_as_int(pairIou[p]));
  }
  __syncthreads();
  for (int p = t; p < P; p += 512) {
    u32 ij = pairI[p];
    int i = (int)(ij >> 16), j = (int)(ij & 0xffffu);
    float x = pairIou[p];
    float c = __int_as_float(compI[i]);
    float x2 = x * x, c2 = c * c;
    float r = (float)exp(-2.0 * ((double)x2 - (double)c2));
    atomicMin(&coefI[j], __float_as_int(r));
  }
  __syncthreads();
  float ns = 0.f;
  if (t < NPRE) {
    ns = sscore[t] * __int_as_float(coefI[t]);
    ns = (ns > U_THR) ? ns : 0.f;
  }
  sk[t] = (((u64)__float_as_uint(ns)) << 32) | (u32)(NPAD - 1 - t);
  __syncthreads();
  for (int k = 2; k <= NPAD; k <<= 1) {
    for (int j = k >> 1; j > 0; j >>= 1) {
      int l = t ^ j;
      if (l > t) {
        u64 a = sk[t], b = sk[l];
        bool sw = ((t & k) == 0) ? (a < b) : (a > b);
        if (sw) { sk[t] = b; sk[l] = a; }
      }
      __syncthreads();
    }
  }
  if (t < MAXOUT) {
    u64 key = sk[t];
    int pos = NPAD - 1 - (int)(key & 0xffffffffu);
    int cand = order[pos];
    topc[t] = cand;
    out[OUT_LBL + t] = (float)labelK[cand];
    out[OUT_SCR + t] = __uint_as_float((u32)(key >> 32));
  }
}

// -------- stage 6: resize weight tables (mimic jax.image.resize f32 math) --------
__global__ __launch_bounds__(1024) void kwts(char* __restrict__ ws) {
  int t = threadIdx.x;
  // resize1 y mid rows: 200 -> 800 (bilinear, 2 taps, border-renormalized)
  for (int r = t; r < MH; r += 1024) {
    float s1 = ((float)r + 0.5f) * 0.25f - 0.5f;
    int t0 = (int)floorf(s1);
    float f = s1 - (float)t0;
    float wa = 1.f - f, wb = f;
    bool ia = (t0 >= 0) && (t0 < HH);
    bool ib = ((t0 + 1) >= 0) && ((t0 + 1) < HH);
    float tw = (ia ? wa : 0.f) + (ib ? wb : 0.f);
    float na = ia ? (wa / tw) : 0.f;
    float nb = ib ? (wb / tw) : 0.f;
    int base; float A, B;
    if (t0 < 0) { base = 0; A = nb; B = 0.f; }
    else if (t0 >= HH - 1) { base = HH - 2; A = 0.f; B = na; }
    else { base = t0; A = na; B = nb; }
    P_I32(OFF_W1YT0)[r] = base;
    P_F32(OFF_W1YA)[r] = A;
    P_F32(OFF_W1YB)[r] = B;
  }
  // resize1 x mid cols: 304 -> 1216
  for (int c = t; c < MW; c += 1024) {
    float s1 = ((float)c + 0.5f) * 0.25f - 0.5f;
    int t0 = (int)floorf(s1);
    float f = s1 - (float)t0;
    float wa = 1.f - f, wb = f;
    bool ia = (t0 >= 0) && (t0 < WW);
    bool ib = ((t0 + 1) >= 0) && ((t0 + 1) < WW);
    float tw = (ia ? wa : 0.f) + (ib ? wb : 0.f);
    float na = ia ? (wa / tw) : 0.f;
    float nb = ib ? (wb / tw) : 0.f;
    int base; float A, B;
    if (t0 < 0) { base = 0; A = nb; B = 0.f; }
    else if (t0 >= WW - 1) { base = WW - 2; A = 0.f; B = na; }
    else { base = t0; A = na; B = nb; }
    P_I32(OFF_W1XT0)[c] = base;
    P_F32(OFF_W1XA)[c] = A;
    P_F32(OFF_W1XB)[c] = B;
  }
  // resize2 y: 800 -> 427 (antialias triangle, kernel_scale = 800/427, <=4 taps)
  for (int o = t; o < OH; o += 1024) {
    const float inv = (float)(800.0 / 427.0);
    float s2 = ((float)o + 0.5f) * inv - 0.5f;
    int rA = (int)ceilf(s2 - inv);
    int rB = (int)floorf(s2 + inv);
    if (rA < 0) rA = 0;
    if (rB > MH - 1) rB = MH - 1;
    float tot = 0.f;
    for (int r = rA; r <= rB; r++) {
      float x = fabsf(s2 - (float)r) / inv;
      float w = 1.f - x; if (w < 0.f) w = 0.f;
      tot += w;
    }
    int base = rA; if (base > MH - 4) base = MH - 4;
    float o4[4] = {0.f, 0.f, 0.f, 0.f};
    for (int r = rA; r <= rB; r++) {
      float x = fabsf(s2 - (float)r) / inv;
      float w = 1.f - x; if (w < 0.f) w = 0.f;
      o4[r - base] += w / tot;
    }
    P_I32(OFF_W2YS)[o] = base;
    float* wp = P_F32(OFF_W2YW) + o * 4;
    wp[0] = o4[0]; wp[1] = o4[1]; wp[2] = o4[2]; wp[3] = o4[3];
  }
  // resize2 x: 1216 -> 640 (kernel_scale = 1.9)
  for (int o = t; o < OW; o += 1024) {
    const float inv = (float)(1216.0 / 640.0);
    float s2 = ((float)o + 0.5f) * inv - 0.5f;
    int rA = (int)ceilf(s2 - inv);
    int rB = (int)floorf(s2 + inv);
    if (rA < 0) rA = 0;
    if (rB > MW - 1) rB = MW - 1;
    float tot = 0.f;
    for (int r = rA; r <= rB; r++) {
      float x = fabsf(s2 - (float)r) / inv;
      float w = 1.f - x; if (w < 0.f) w = 0.f;
      tot += w;
    }
    int base = rA; if (base > MW - 4) base = MW - 4;
    float o4[4] = {0.f, 0.f, 0.f, 0.f};
    for (int r = rA; r <= rB; r++) {
      float x = fabsf(s2 - (float)r) / inv;
      float w = 1.f - x; if (w < 0.f) w = 0.f;
      o4[r - base] += w / tot;
    }
    P_I32(OFF_W2XS)[o] = base;
    float* wp = P_F32(OFF_W2XW) + o * 4;
    wp[0] = o4[0]; wp[1] = o4[1]; wp[2] = o4[2]; wp[3] = o4[3];
  }
}

// -------- stage 7: fused double-resize + binarize, one block per (mask, out-row) --------
__global__ __launch_bounds__(256) void kout(const float* __restrict__ segx, const float* __restrict__ segy,
                                            char* __restrict__ ws, float* __restrict__ out) {
  __shared__ float t1[4][WW];   // stage-1 vertical transform of the 4 needed mid rows
  __shared__ float up[4][MW];   // full mid-resolution rows (f32-rounded like the reference)
  int bx = blockIdx.x;
  int kk = bx / OH;
  int oy = bx - kk * OH;
  int tid = threadIdx.x;
  int cand = P_I32(OFF_TOPC)[kk];
  const float* X = segx + (size_t)P_I32(OFF_XIND)[cand] * NPIX;
  const float* Y = segy + (size_t)P_I32(OFF_YIND)[cand] * NPIX;
  int rbase = P_I32(OFF_W2YS)[oy];
  const int* w1yT0 = P_I32(OFF_W1YT0);
  const float* w1yA = P_F32(OFF_W1YA);
  const float* w1yB = P_F32(OFF_W1YB);
  for (int idx = tid; idx < 4 * WW; idx += 256) {
    int m = idx / WW;
    int u = idx - m * WW;
    int r = rbase + m;
    int t0 = w1yT0[r];
    float A = w1yA[r], B = w1yB[r];
    float s0 = X[t0 * WW + u] * Y[t0 * WW + u];
    float s1 = X[(t0 + 1) * WW + u] * Y[(t0 + 1) * WW + u];
    t1[m][u] = fmaf(B, s1, A * s0);
  }
  __syncthreads();
  const int* w1xT0 = P_I32(OFF_W1XT0);
  const float* w1xA = P_F32(OFF_W1XA);
  const float* w1xB = P_F32(OFF_W1XB);
  for (int idx = tid; idx < 4 * MW; idx += 256) {
    int m = idx / MW;
    int cc = idx - m * MW;
    int u0 = w1xT0[cc];
    up[m][cc] = fmaf(w1xB[cc], t1[m][u0 + 1], w1xA[cc] * t1[m][u0]);
  }
  __syncthreads();
  float wy[4];
  {
    const float* wyp = P_F32(OFF_W2YW) + oy * 4;
    wy[0] = wyp[0]; wy[1] = wyp[1]; wy[2] = wyp[2]; wy[3] = wyp[3];
  }
  const int* w2xS = P_I32(OFF_W2XS);
  const float* w2xW = P_F32(OFF_W2XW);
  size_t obase = ((size_t)kk * OH + oy) * OW;
  for (int ox = tid; ox < OW; ox += 256) {
    int cb = w2xS[ox];
    const float* wx = w2xW + ox * 4;
    float acc = 0.f;
    #pragma unroll
    for (int q = 0; q < 4; q++) {
      int cc = cb + q;
      float t2 = 0.f;
      #pragma unroll
      for (int m = 0; m < 4; m++) t2 = fmaf(wy[m], up[m][cc], t2);
      acc = fmaf(wx[q], t2, acc);
    }
    out[obase + ox] = (acc > M_THR) ? 1.0f : 0.0f;
  }
}

extern "C" void kernel_launch(void* const* d_in, const int* in_sizes, int n_in,
                              void* d_out, int out_size, void* d_ws, size_t ws_size,
                              hipStream_t stream) {
  (void)in_sizes; (void)n_in; (void)out_size; (void)ws_size;
  const float* cate = (const float*)d_in[0];
  const float* segx = (const float*)d_in[1];
  const float* segy = (const float*)d_in[2];
  char* ws = (char*)d_ws;
  float* out = (float*)d_out;

  hipMemsetAsync(ws, 0, ZERO_BYTES, stream);

  dim3 gFlat((NFLAT + 255) / 256);
  hipLaunchKernelGGL(kh1, gFlat, dim3(256), 0, stream, cate, ws);
  hipLaunchKernelGGL(kc1, dim3(1), dim3(1024), 0, stream, ws);
  hipLaunchKernelGGL(kh2, gFlat, dim3(256), 0, stream, cate, ws);
  hipLaunchKernelGGL(kc2, dim3(1), dim3(1), 0, stream, ws);
  hipLaunchKernelGGL(kg, gFlat, dim3(256), 0, stream, cate, ws);
  hipLaunchKernelGGL(ksel, dim3(1), dim3(1024), 0, stream, ws);
  hipLaunchKernelGGL(kmask, dim3(NPRE), dim3(256), 0, stream, segx, segy, ws);
  hipLaunchKernelGGL(ksort500, dim3(1), dim3(512), 0, stream, ws);
  hipLaunchKernelGGL(kpairs, dim3(1), dim3(512), 0, stream, ws);
  hipLaunchKernelGGL(kpiou, dim3(2048), dim3(64), 0, stream, ws);
  hipLaunchKernelGGL(kwts, dim3(1), dim3(1024), 0, stream, ws);
  hipLaunchKernelGGL(knms, dim3(1), dim3(512), 0, stream, ws, out);
  hipLaunchKernelGGL(kout, dim3(MAXOUT * OH), dim3(256), 0, stream, segx, segy, ws, out);
}